// Round 15
// baseline (146.359 us; speedup 1.0000x reference)
//
#include <hip/hip_runtime.h>
#include <cstdint>
#include <cstddef>

typedef unsigned short u16;
typedef short bf16x8 __attribute__((ext_vector_type(8)));
typedef unsigned short u16x8 __attribute__((ext_vector_type(8)));
typedef float f32x4 __attribute__((ext_vector_type(4)));
typedef float f32x16 __attribute__((ext_vector_type(16)));
typedef unsigned u32x2 __attribute__((ext_vector_type(2)));

__device__ __forceinline__ u16 f2bf(float x) {
    union { float f; unsigned int u; } v; v.f = x;
    unsigned int u = v.u;
    unsigned int r = (u + 0x7fffu + ((u >> 16) & 1u)) >> 16;
    return (u16)r;
}

__device__ __forceinline__ unsigned cvtpk(float lo, float hi) {
    unsigned r;
    asm("v_cvt_pk_bf16_f32 %0, %1, %2" : "=v"(r) : "v"(lo), "v"(hi));
    return r;
}

__device__ __forceinline__ float exp2v(float x) {
    float y;
    asm("v_exp_f32 %0, %1" : "=v"(y) : "v"(x));
    return y;
}

// async global->LDS, 16B per lane. dest = wave-uniform base; lane i lands at base + i*16B.
__device__ __forceinline__ void load_lds16(const void* g, void* l) {
    __builtin_amdgcn_global_load_lds((const __attribute__((address_space(1))) void*)g,
                                     (__attribute__((address_space(3))) void*)l, 16, 0, 0);
}

// ---------------- casts ----------------
__global__ void cast_f32_bf16(const float* __restrict__ in, u16* __restrict__ out, int n) {
    int i = (blockIdx.x * blockDim.x + threadIdx.x) * 4;
    int stride = gridDim.x * blockDim.x * 4;
    for (; i < n; i += stride) {
        float4 f = *reinterpret_cast<const float4*>(in + i);
        ushort4 o;
        o.x = f2bf(f.x); o.y = f2bf(f.y); o.z = f2bf(f.z); o.w = f2bf(f.w);
        *reinterpret_cast<ushort4*>(out + i) = o;
    }
}

__global__ void cast_w4(const float* __restrict__ w0, const float* __restrict__ w1,
                        const float* __restrict__ w2, const float* __restrict__ w3,
                        u16* __restrict__ out, int nw) {
    const int wsel = blockIdx.y;
    const float* in = (wsel == 0) ? w0 : (wsel == 1) ? w1 : (wsel == 2) ? w2 : w3;
    u16* o = out + (size_t)wsel * nw;
    int i = (blockIdx.x * blockDim.x + threadIdx.x) * 4;
    int stride = gridDim.x * blockDim.x * 4;
    for (; i < nw; i += stride) {
        float4 f = *reinterpret_cast<const float4*>(in + i);
        ushort4 v;
        v.x = f2bf(f.x); v.y = f2bf(f.y); v.z = f2bf(f.z); v.w = f2bf(f.w);
        *reinterpret_cast<ushort4*>(o + i) = v;
    }
}

// ============ QKV GEMM v2: 128x256 tile, 4 waves x (64x128)/wave, BK=32, triple-buffer ============
// Higher arithmetic intensity: per wave per K-step 12KB LDS reads / 32 MFMAs (42.7 FLOP/B)
// vs 8KB/16 (32 FLOP/B) before -> LDS no longer the binding pipe.
// acc 128 AGPR + ~80 VGPR <= 256: 2 waves/SIMD, 2 blocks/CU.
__global__ __launch_bounds__(256, 2) void gemm_qkv4(const u16* __restrict__ A,
                                                    const u16* __restrict__ Bw,
                                                    u16* __restrict__ qkout,
                                                    u16* __restrict__ vtg) {
    constexpr int K = 1024;
    __shared__ u16 smem[36864];   // 3 x (A 4096 + B 8192) u16 = 72 KB

    const int tid  = threadIdx.x;
    const int m0   = blockIdx.x * 128;
    const int n0   = blockIdx.y * 256;
    const int wid  = tid >> 6, lane = tid & 63;
    const int fr   = lane & 15, g = lane >> 4;
    const int wm   = wid >> 1, wn = wid & 1;

    // staging: 6 x 16B per thread per K-step; row sr covers 64-row groups, slot tid&3.
    const int sr   = tid >> 2;                       // 0..63
    const int ssrc = (tid & 3) ^ ((sr >> 1) & 3);    // swizzled source slot (row+64: same swz)
    const int wbu  = wid * 512;                      // wave-uniform chunk base (u16)
    const u16* pA0 = A  + (size_t)(m0 + sr) * K + ssrc * 8;
    const u16* pA1 = A  + (size_t)(m0 + 64 + sr) * K + ssrc * 8;
    const u16* pB0 = Bw + (size_t)(n0 + sr) * K + ssrc * 8;
    const u16* pB1 = Bw + (size_t)(n0 + 64 + sr) * K + ssrc * 8;
    const u16* pB2 = Bw + (size_t)(n0 + 128 + sr) * K + ssrc * 8;
    const u16* pB3 = Bw + (size_t)(n0 + 192 + sr) * K + ssrc * 8;

    int offA[4], offB[8];
#pragma unroll
    for (int mf = 0; mf < 4; ++mf) {
        const int row = wm * 64 + mf * 16 + fr;
        offA[mf] = row * 32 + (g ^ ((row >> 1) & 3)) * 8;
    }
#pragma unroll
    for (int nf = 0; nf < 8; ++nf) {
        const int row = wn * 128 + nf * 16 + fr;
        offB[nf] = 4096 + row * 32 + (g ^ ((row >> 1) & 3)) * 8;
    }

    f32x4 acc[4][8];
#pragma unroll
    for (int i = 0; i < 4; ++i)
#pragma unroll
        for (int j = 0; j < 8; ++j) acc[i][j] = f32x4{0.f, 0.f, 0.f, 0.f};

#define ISSUE(BUF) {                                                     \
        u16* bb_ = &smem[(BUF) * 12288 + wbu];                           \
        load_lds16(pA0, bb_);                                            \
        load_lds16(pA1, bb_ + 2048);                                     \
        load_lds16(pB0, bb_ + 4096);                                     \
        load_lds16(pB1, bb_ + 6144);                                     \
        load_lds16(pB2, bb_ + 8192);                                     \
        load_lds16(pB3, bb_ + 10240);                                    \
        pA0 += 32; pA1 += 32; pB0 += 32; pB1 += 32; pB2 += 32; pB3 += 32; }

    ISSUE(0);
    ISSUE(1);

    constexpr int NT = K >> 5;   // 32
    int bu = 0;
    for (int t = 0; t < NT; ++t) {
        if (t < NT - 1) asm volatile("s_waitcnt vmcnt(6)\n\ts_barrier" ::: "memory");
        else            asm volatile("s_waitcnt vmcnt(0)\n\ts_barrier" ::: "memory");

        if (t + 2 < NT) {
            const int b2 = (bu == 0) ? 2 : bu - 1;
            ISSUE(b2);
        }

        const u16* Tb = &smem[bu * 12288];
        bf16x8 a[4];
#pragma unroll
        for (int mf = 0; mf < 4; ++mf)
            a[mf] = *reinterpret_cast<const bf16x8*>(&Tb[offA[mf]]);

        __builtin_amdgcn_s_setprio(1);
#pragma unroll
        for (int nf = 0; nf < 8; ++nf) {
            bf16x8 bv = *reinterpret_cast<const bf16x8*>(&Tb[offB[nf]]);
#pragma unroll
            for (int mf = 0; mf < 4; ++mf)
                acc[mf][nf] = __builtin_amdgcn_mfma_f32_16x16x32_bf16(
                    a[mf], bv, acc[mf][nf], 0, 0, 0);
        }
        __builtin_amdgcn_s_setprio(0);

        bu = (bu == 2) ? 0 : bu + 1;
    }
#undef ISSUE

    __syncthreads();   // compute done; smem free for epilogue restaging
    char* sb = reinterpret_cast<char*>(smem);
    if (n0 < 2048) {
        const float osc = (n0 < 1024) ? 0.18033688011112042f : 1.0f;  // log2(e)/8 on Q
#pragma unroll
        for (int mf = 0; mf < 4; ++mf)
#pragma unroll
            for (int nf = 0; nf < 8; ++nf) {
                const int col = wn * 128 + nf * 16 + fr;
#pragma unroll
                for (int i = 0; i < 4; ++i) {
                    const int row  = wm * 64 + mf * 16 + g * 4 + i;
                    const int byte = row * 512 + ((col * 2) ^ (((row >> 2) & 3) << 5));
                    *reinterpret_cast<u16*>(sb + byte) = f2bf(acc[mf][nf][i] * osc);
                }
            }
        __syncthreads();
        {
            const int row = tid >> 1;                 // 0..127
            const int swz = ((row >> 2) & 3) << 5;
#pragma unroll
            for (int p = 0; p < 16; ++p) {
                const int sl   = (tid & 1) + p * 2;   // 0..31
                const int byte = row * 512 + ((sl * 16) ^ swz);
                u16x8 v = *reinterpret_cast<const u16x8*>(sb + byte);
                *reinterpret_cast<u16x8*>(
                    &qkout[(size_t)(m0 + row) * 2048 + n0 + sl * 8]) = v;
            }
        }
    } else {
        const int bb = m0 >> 11, tloc = m0 & 2047;
#pragma unroll
        for (int mf = 0; mf < 4; ++mf)
#pragma unroll
            for (int nf = 0; nf < 8; ++nf) {
                const int nl  = wn * 128 + nf * 16 + fr;      // 0..255
                const int ml0 = wm * 64 + mf * 16 + g * 4;    // 0..124
                const int f   = (nl & 7) << 5;
                uint2 pk;
                pk.x = cvtpk(acc[mf][nf][0], acc[mf][nf][1]);
                pk.y = cvtpk(acc[mf][nf][2], acc[mf][nf][3]);
                *reinterpret_cast<uint2*>(sb + nl * 256 + ((ml0 * 2) ^ f)) = pk;
            }
        __syncthreads();
#pragma unroll
        for (int h = 0; h < 2; ++h) {
            const int nl = h * 128 + (tid >> 1);              // 0..255
            const int f  = (nl & 7) << 5;
#pragma unroll
            for (int p = 0; p < 8; ++p) {
                const int sl   = (tid & 1) + p * 2;           // 0..15
                const int byte = nl * 256 + ((sl * 16) ^ f);
                u16x8 v = *reinterpret_cast<const u16x8*>(sb + byte);
                *reinterpret_cast<u16x8*>(
                    &vtg[(size_t)(bb * 1024 + (n0 - 2048) + nl) * 2048 +
                         tloc + sl * 8]) = v;
            }
        }
    }
}

// ============ GEMM: 128x256 tile, BK=32, 512 thr, triple-buffered LDS (72KB) ============
// (R10 version, MODE 0 only — Wo projection, fp32 out.)
template <int MODE>
__global__ __launch_bounds__(512, 4) void gemm128(const u16* __restrict__ A,
                                                  const u16* __restrict__ Bw,
                                                  void* __restrict__ outp,
                                                  u16* __restrict__ vtg,
                                                  int N, int K) {
    __shared__ u16 smem[36864];

    const int tid  = threadIdx.x;
    const int m0   = blockIdx.x * 128;
    const int n0   = blockIdx.y * 256;
    const int wid  = tid >> 6, lane = tid & 63;
    const int fr   = lane & 15, g = lane >> 4;
    const int wm   = wid >> 2, wn = wid & 3;

    const int r0   = tid >> 2;
    const int ssrc = (tid & 3) ^ ((r0 >> 1) & 3);
    const int wbu  = (tid & ~63) * 8;
    const u16* pA  = A  + (size_t)(m0 + r0) * K + ssrc * 8;
    const u16* pB0 = Bw + (size_t)(n0 + r0) * K + ssrc * 8;
    const u16* pB1 = Bw + (size_t)(n0 + r0 + 128) * K + ssrc * 8;

    int offA[4], offB[4];
#pragma unroll
    for (int mf = 0; mf < 4; ++mf) {
        const int row = wm * 64 + mf * 16 + fr;
        offA[mf] = row * 32 + (g ^ ((row >> 1) & 3)) * 8;
    }
#pragma unroll
    for (int nf = 0; nf < 4; ++nf) {
        const int row = wn * 64 + nf * 16 + fr;
        offB[nf] = 4096 + row * 32 + (g ^ ((row >> 1) & 3)) * 8;
    }

    f32x4 acc[4][4];
#pragma unroll
    for (int i = 0; i < 4; ++i)
#pragma unroll
        for (int j = 0; j < 4; ++j) acc[i][j] = f32x4{0.f, 0.f, 0.f, 0.f};

#define ISSUE(BUF) {                                                   \
        load_lds16(pA,  &smem[(BUF) * 12288 + wbu]);                   \
        load_lds16(pB0, &smem[(BUF) * 12288 + 4096 + wbu]);            \
        load_lds16(pB1, &smem[(BUF) * 12288 + 8192 + wbu]);            \
        pA += 32; pB0 += 32; pB1 += 32; }

    ISSUE(0);
    ISSUE(1);

    const int NT = K >> 5;
    int bu = 0;
    for (int t = 0; t < NT; ++t) {
        if (t < NT - 1) asm volatile("s_waitcnt vmcnt(4)\n\ts_barrier" ::: "memory");
        else            asm volatile("s_waitcnt vmcnt(0)\n\ts_barrier" ::: "memory");

        if (t + 2 < NT) {
            const int b2 = (bu == 0) ? 2 : bu - 1;
            ISSUE(b2);
        }

        const u16* Tb = &smem[bu * 12288];
        bf16x8 a[4], bv[4];
#pragma unroll
        for (int mf = 0; mf < 4; ++mf)
            a[mf] = *reinterpret_cast<const bf16x8*>(&Tb[offA[mf]]);
#pragma unroll
        for (int nf = 0; nf < 4; ++nf)
            bv[nf] = *reinterpret_cast<const bf16x8*>(&Tb[offB[nf]]);

        __builtin_amdgcn_s_setprio(1);
#pragma unroll
        for (int mf = 0; mf < 4; ++mf)
#pragma unroll
            for (int nf = 0; nf < 4; ++nf)
                acc[mf][nf] = __builtin_amdgcn_mfma_f32_16x16x32_bf16(
                    a[mf], bv[nf], acc[mf][nf], 0, 0, 0);
        __builtin_amdgcn_s_setprio(0);

        bu = (bu == 2) ? 0 : bu + 1;
    }
#undef ISSUE

    if constexpr (MODE == 0) {
        float* C = (float*)outp;
#pragma unroll
        for (int mf = 0; mf < 4; ++mf)
#pragma unroll
            for (int nf = 0; nf < 4; ++nf)
#pragma unroll
                for (int i = 0; i < 4; ++i)
                    C[(size_t)(m0 + wm * 64 + mf * 16 + g * 4 + i) * N +
                      n0 + wn * 64 + nf * 16 + fr] = acc[mf][nf][i];
    }
    (void)vtg;
}

// ---------------- causal flash attention: 4-wave blocks, whole grid co-resident ----------------
// grid (1024), 256 thr: block = one 128-row q-tile; wave w owns rows w*32..w*32+31.
// qt via balance table: [15,12,2,1, 14,13,3,0, 11,8,6,5, 10,9,7,4] (groups of 4 sum 30).
__global__ __launch_bounds__(256, 4) void attn_fwd(const u16* __restrict__ qk,
                                                   const u16* __restrict__ vtg,
                                                   u16* __restrict__ Y) {
    constexpr int T = 2048, DQK = 2048, DOUT = 1024;
    const int idx = blockIdx.x;
    const int bh  = idx & 63;
    const int tsel = ((idx >> 6) & 3) * 4 + (idx >> 8);
    const int qt = (int)((0x479A568B03DE12CFull >> (tsel * 4)) & 15);
    const int b  = bh >> 4, hd = bh & 15;
    const int tid = threadIdx.x, w = tid >> 6, lane = tid & 63;
    const int qloc = lane & 31, h2 = lane >> 5;

    __shared__ u16 Ks[2][4096];   // [64 kv][64 d] linear, slot^(row&7) swizzle (8KB/buf)
    __shared__ u16 Vs[2][4096];   // [64 d][64 kv] linear, same swizzle

    const size_t rowb = (size_t)b * T;

    const int r0s = tid >> 3;                   // 0..31
    const int sc  = ((tid & 7) ^ (r0s & 7)) * 8;
    const int ldst = w * 512;                   // wave-uniform chunk base (u16)

    int off[4];
#pragma unroll
    for (int ks = 0; ks < 4; ++ks)
        off[ks] = qloc * 64 + (((2 * ks + h2) ^ (qloc & 7)) * 8);

#define BUILD_PA(sv, RB, dst) {                                               \
        unsigned wa  = cvtpk(sv[RB + 0], sv[RB + 1]);                         \
        unsigned wb2 = cvtpk(sv[RB + 2], sv[RB + 3]);                         \
        unsigned wc2 = cvtpk(sv[RB + 4], sv[RB + 5]);                         \
        unsigned wd  = cvtpk(sv[RB + 6], sv[RB + 7]);                         \
        u32x2 r0 = __builtin_amdgcn_permlane32_swap(wa, wc2, false, false);   \
        u32x2 r1 = __builtin_amdgcn_permlane32_swap(wb2, wd, false, false);   \
        dst.x = r0.x; dst.y = r1.x; dst.z = r0.y; dst.w = r1.y; }

#define PV_STEP(pa, KS, RBOFF, oacc) {                                        \
        bf16x8 vf_ = *reinterpret_cast<const bf16x8*>(&Vb[off[KS] + (RBOFF)]); \
        oacc = __builtin_amdgcn_mfma_f32_32x32x16_bf16(                       \
            *reinterpret_cast<const bf16x8*>(&pa), vf_, oacc, 0, 0, 0); }

    const int q0 = qt * 128;
    const int wq = q0 + w * 32;
    const int NT = 2 * qt + 2;

    bf16x8 qf[4];
#pragma unroll
    for (int ks = 0; ks < 4; ++ks)
        qf[ks] = *reinterpret_cast<const bf16x8*>(
            &qk[(rowb + wq + qloc) * DQK + hd * 64 + ks * 16 + h2 * 8]);

    f32x16 o0, o1;
#pragma unroll
    for (int i = 0; i < 16; ++i) { o0[i] = 0.f; o1[i] = 0.f; }
    float lp = 0.f;

    const u16* kp = qk  + (rowb + r0s) * DQK + 1024 + hd * 64 + sc;
    const u16* vp = vtg + ((size_t)bh * 64 + r0s) * T + sc;

    load_lds16(kp,            &Ks[0][ldst]);
    load_lds16(kp + 32 * DQK, &Ks[0][2048 + ldst]);
    load_lds16(vp,            &Vs[0][ldst]);
    load_lds16(vp + 32 * T,   &Vs[0][2048 + ldst]);
    kp += 64 * DQK; vp += 64;

    for (int kt = 0; kt < NT; ++kt) {
        __syncthreads();

        if (kt + 1 < NT) {
            const int nb = (kt + 1) & 1;
            load_lds16(kp,            &Ks[nb][ldst]);
            load_lds16(kp + 32 * DQK, &Ks[nb][2048 + ldst]);
            load_lds16(vp,            &Vs[nb][ldst]);
            load_lds16(vp + 32 * T,   &Vs[nb][2048 + ldst]);
            kp += 64 * DQK; vp += 64;
        }

        const int k0 = kt * 64;
        if (k0 <= wq + 31) {
            const u16* Kb = Ks[kt & 1];
            const u16* Vb = Vs[kt & 1];
            const bool do1 = (k0 + 32 <= wq + 31);
            const bool dm  = (k0 + 63 > wq);
            const int qg = wq + qloc;

            f32x16 st0, st1;
#pragma unroll
            for (int i = 0; i < 16; ++i) { st0[i] = 0.f; st1[i] = 0.f; }

            __builtin_amdgcn_s_setprio(1);
#pragma unroll
            for (int ks = 0; ks < 4; ++ks) {
                bf16x8 kf = *reinterpret_cast<const bf16x8*>(&Kb[off[ks]]);
                st0 = __builtin_amdgcn_mfma_f32_32x32x16_bf16(kf, qf[ks], st0, 0, 0, 0);
            }
            if (do1) {
#pragma unroll
                for (int ks = 0; ks < 4; ++ks) {
                    bf16x8 kf = *reinterpret_cast<const bf16x8*>(&Kb[off[ks] + 2048]);
                    st1 = __builtin_amdgcn_mfma_f32_32x32x16_bf16(kf, qf[ks], st1, 0, 0, 0);
                }
            }
            __builtin_amdgcn_s_setprio(0);

#pragma unroll
            for (int i = 0; i < 16; ++i) st0[i] = exp2v(st0[i]);
            if (dm) {
#pragma unroll
                for (int r = 0; r < 16; ++r) {
                    const int crow = (r & 3) + 8 * (r >> 2) + 4 * h2;
                    if (k0 + crow > qg) st0[r] = 0.f;
                }
            }
            {
                float l0 = 0.f, l1 = 0.f, l2 = 0.f, l3 = 0.f;
#pragma unroll
                for (int i = 0; i < 4; ++i) {
                    l0 += st0[i]; l1 += st0[4 + i]; l2 += st0[8 + i]; l3 += st0[12 + i];
                }
                lp += (l0 + l1) + (l2 + l3);
            }
            uint4 pa0, pa1;
            BUILD_PA(st0, 0, pa0);
            BUILD_PA(st0, 8, pa1);
            __builtin_amdgcn_s_setprio(1);
            PV_STEP(pa0, 0, 0, o0);
            PV_STEP(pa1, 1, 0, o0);
            PV_STEP(pa0, 0, 2048, o1);
            PV_STEP(pa1, 1, 2048, o1);
            __builtin_amdgcn_s_setprio(0);

            if (do1) {
#pragma unroll
                for (int i = 0; i < 16; ++i) st1[i] = exp2v(st1[i]);
                if (dm) {
#pragma unroll
                    for (int r = 0; r < 16; ++r) {
                        const int crow = (r & 3) + 8 * (r >> 2) + 4 * h2;
                        if (k0 + 32 + crow > qg) st1[r] = 0.f;
                    }
                }
                {
                    float l0 = 0.f, l1 = 0.f, l2 = 0.f, l3 = 0.f;
#pragma unroll
                    for (int i = 0; i < 4; ++i) {
                        l0 += st1[i]; l1 += st1[4 + i]; l2 += st1[8 + i]; l3 += st1[12 + i];
                    }
                    lp += (l0 + l1) + (l2 + l3);
                }
                uint4 pa2, pa3;
                BUILD_PA(st1, 0, pa2);
                BUILD_PA(st1, 8, pa3);
                __builtin_amdgcn_s_setprio(1);
                PV_STEP(pa2, 2, 0, o0);
                PV_STEP(pa3, 3, 0, o0);
                PV_STEP(pa2, 2, 2048, o1);
                PV_STEP(pa3, 3, 2048, o1);
                __builtin_amdgcn_s_setprio(0);
            }
        }
    }

    const float lf = lp + __shfl_xor(lp, 32);
    const float linv = 1.0f / lf;
#pragma unroll
    for (int r = 0; r < 16; ++r) {
        const int crow = (r & 3) + 8 * (r >> 2) + 4 * h2;
        const float rl = __shfl(linv, crow);
        const size_t yrow = rowb + wq + crow;
        Y[yrow * DOUT + hd * 64 + qloc]      = (u16)cvtpk(o0[r] * rl, 0.f);
        Y[yrow * DOUT + hd * 64 + 32 + qloc] = (u16)cvtpk(o1[r] * rl, 0.f);
    }
#undef BUILD_PA
#undef PV_STEP
}

extern "C" void kernel_launch(void* const* d_in, const int* in_sizes, int n_in,
                              void* d_out, int out_size, void* d_ws, size_t ws_size,
                              hipStream_t stream) {
    const float* x  = (const float*)d_in[0];
    const float* Wq = (const float*)d_in[1];
    const float* Wk = (const float*)d_in[2];
    const float* Wv = (const float*)d_in[3];
    const float* Wo = (const float*)d_in[4];

    constexpr int B = 4, T = 2048, D = 1024;
    constexpr int M = B * T;
    const int nx = in_sizes[0];
    const int nw = in_sizes[1];

    char* ws = (char*)d_ws;
    u16* xb   = (u16*)(ws);
    u16* qkb  = (u16*)(ws + (16ull << 20));
    u16* vtg  = (u16*)(ws + (48ull << 20));
    u16* yb   = (u16*)(ws + (64ull << 20));
    u16* wqkv = (u16*)(ws + (80ull << 20));   // Wq,Wk,Wv then Wo contiguous
    u16* wob  = wqkv + 3 * (size_t)nw;

    cast_f32_bf16<<<2048, 256, 0, stream>>>(x, xb, nx);
    cast_w4<<<dim3(256, 4), 256, 0, stream>>>(Wq, Wk, Wv, Wo, wqkv, nw);

    gemm_qkv4<<<dim3(M / 128, 3072 / 256), 256, 0, stream>>>(xb, wqkv, qkb, vtg);

    attn_fwd<<<dim3(1024), 256, 0, stream>>>(qkb, vtg, yb);

    gemm128<0><<<dim3(M / 128, D / 256), 512, 0, stream>>>(yb, wob, d_out, nullptr, D, D);
}

// Round 16
// 144.469 us; speedup vs baseline: 1.0131x; 1.0131x over previous
//
#include <hip/hip_runtime.h>
#include <cstdint>
#include <cstddef>

typedef unsigned short u16;
typedef short bf16x8 __attribute__((ext_vector_type(8)));
typedef unsigned short u16x8 __attribute__((ext_vector_type(8)));
typedef float f32x4 __attribute__((ext_vector_type(4)));
typedef float f32x16 __attribute__((ext_vector_type(16)));
typedef unsigned u32x2 __attribute__((ext_vector_type(2)));

__device__ __forceinline__ u16 f2bf(float x) {
    union { float f; unsigned int u; } v; v.f = x;
    unsigned int u = v.u;
    unsigned int r = (u + 0x7fffu + ((u >> 16) & 1u)) >> 16;
    return (u16)r;
}

__device__ __forceinline__ unsigned cvtpk(float lo, float hi) {
    unsigned r;
    asm("v_cvt_pk_bf16_f32 %0, %1, %2" : "=v"(r) : "v"(lo), "v"(hi));
    return r;
}

__device__ __forceinline__ float exp2v(float x) {
    float y;
    asm("v_exp_f32 %0, %1" : "=v"(y) : "v"(x));
    return y;
}

// async global->LDS, 16B per lane. dest = wave-uniform base; lane i lands at base + i*16B.
__device__ __forceinline__ void load_lds16(const void* g, void* l) {
    __builtin_amdgcn_global_load_lds((const __attribute__((address_space(1))) void*)g,
                                     (__attribute__((address_space(3))) void*)l, 16, 0, 0);
}

// ---------------- casts ----------------
__global__ void cast_f32_bf16(const float* __restrict__ in, u16* __restrict__ out, int n) {
    int i = (blockIdx.x * blockDim.x + threadIdx.x) * 4;
    int stride = gridDim.x * blockDim.x * 4;
    for (; i < n; i += stride) {
        float4 f = *reinterpret_cast<const float4*>(in + i);
        ushort4 o;
        o.x = f2bf(f.x); o.y = f2bf(f.y); o.z = f2bf(f.z); o.w = f2bf(f.w);
        *reinterpret_cast<ushort4*>(out + i) = o;
    }
}

__global__ void cast_w4(const float* __restrict__ w0, const float* __restrict__ w1,
                        const float* __restrict__ w2, const float* __restrict__ w3,
                        u16* __restrict__ out, int nw) {
    const int wsel = blockIdx.y;
    const float* in = (wsel == 0) ? w0 : (wsel == 1) ? w1 : (wsel == 2) ? w2 : w3;
    u16* o = out + (size_t)wsel * nw;
    int i = (blockIdx.x * blockDim.x + threadIdx.x) * 4;
    int stride = gridDim.x * blockDim.x * 4;
    for (; i < nw; i += stride) {
        float4 f = *reinterpret_cast<const float4*>(in + i);
        ushort4 v;
        v.x = f2bf(f.x); v.y = f2bf(f.y); v.z = f2bf(f.z); v.w = f2bf(f.w);
        *reinterpret_cast<ushort4*>(o + i) = v;
    }
}

// ============ GEMM: 128x256 tile, BK=32, 512 thr, triple-buffered LDS (72KB) ============
// (R14 version; vmcnt(3) fix: 3 loads/thread/tile -> waiting to <=3 outstanding guarantees
//  the CURRENT tile's loads all landed while next tile's 3 stay in flight.)
template <int MODE>
__global__ __launch_bounds__(512, 4) void gemm128(const u16* __restrict__ A,
                                                  const u16* __restrict__ Bw,
                                                  void* __restrict__ outp,
                                                  u16* __restrict__ vtg,
                                                  int N, int K) {
    __shared__ u16 smem[36864];   // 3 x (A 4096 + B 8192) u16 = 72 KB

    const int tid  = threadIdx.x;
    const int m0   = blockIdx.x * 128;
    const int n0   = blockIdx.y * 256;
    const int wid  = tid >> 6, lane = tid & 63;
    const int fr   = lane & 15, g = lane >> 4;
    const int wm   = wid >> 2, wn = wid & 3;

    const int r0   = tid >> 2;
    const int ssrc = (tid & 3) ^ ((r0 >> 1) & 3);
    const int wbu  = (tid & ~63) * 8;
    const u16* pA  = A  + (size_t)(m0 + r0) * K + ssrc * 8;
    const u16* pB0 = Bw + (size_t)(n0 + r0) * K + ssrc * 8;
    const u16* pB1 = Bw + (size_t)(n0 + r0 + 128) * K + ssrc * 8;

    int offA[4], offB[4];
#pragma unroll
    for (int mf = 0; mf < 4; ++mf) {
        const int row = wm * 64 + mf * 16 + fr;
        offA[mf] = row * 32 + (g ^ ((row >> 1) & 3)) * 8;
    }
#pragma unroll
    for (int nf = 0; nf < 4; ++nf) {
        const int row = wn * 64 + nf * 16 + fr;
        offB[nf] = 4096 + row * 32 + (g ^ ((row >> 1) & 3)) * 8;
    }

    f32x4 acc[4][4];
#pragma unroll
    for (int i = 0; i < 4; ++i)
#pragma unroll
        for (int j = 0; j < 4; ++j) acc[i][j] = f32x4{0.f, 0.f, 0.f, 0.f};

#define ISSUE(BUF) {                                                   \
        load_lds16(pA,  &smem[(BUF) * 12288 + wbu]);                   \
        load_lds16(pB0, &smem[(BUF) * 12288 + 4096 + wbu]);            \
        load_lds16(pB1, &smem[(BUF) * 12288 + 8192 + wbu]);            \
        pA += 32; pB0 += 32; pB1 += 32; }

    ISSUE(0);
    ISSUE(1);

    const int NT = K >> 5;
    int bu = 0;
    for (int t = 0; t < NT; ++t) {
        if (t < NT - 1) asm volatile("s_waitcnt vmcnt(3)\n\ts_barrier" ::: "memory");
        else            asm volatile("s_waitcnt vmcnt(0)\n\ts_barrier" ::: "memory");

        if (t + 2 < NT) {
            const int b2 = (bu == 0) ? 2 : bu - 1;
            ISSUE(b2);
        }

        const u16* Tb = &smem[bu * 12288];
        bf16x8 a[4], bv[4];
#pragma unroll
        for (int mf = 0; mf < 4; ++mf)
            a[mf] = *reinterpret_cast<const bf16x8*>(&Tb[offA[mf]]);
#pragma unroll
        for (int nf = 0; nf < 4; ++nf)
            bv[nf] = *reinterpret_cast<const bf16x8*>(&Tb[offB[nf]]);

        __builtin_amdgcn_s_setprio(1);
#pragma unroll
        for (int mf = 0; mf < 4; ++mf)
#pragma unroll
            for (int nf = 0; nf < 4; ++nf)
                acc[mf][nf] = __builtin_amdgcn_mfma_f32_16x16x32_bf16(
                    a[mf], bv[nf], acc[mf][nf], 0, 0, 0);
        __builtin_amdgcn_s_setprio(0);

        bu = (bu == 2) ? 0 : bu + 1;
    }
#undef ISSUE

    if constexpr (MODE == 0) {
        float* C = (float*)outp;
#pragma unroll
        for (int mf = 0; mf < 4; ++mf)
#pragma unroll
            for (int nf = 0; nf < 4; ++nf)
#pragma unroll
                for (int i = 0; i < 4; ++i)
                    C[(size_t)(m0 + wm * 64 + mf * 16 + g * 4 + i) * N +
                      n0 + wn * 64 + nf * 16 + fr] = acc[mf][nf][i];
    } else {
        __syncthreads();
        char* sb = reinterpret_cast<char*>(smem);
        if (n0 < 2048) {
            const float osc = (n0 < 1024) ? 0.18033688011112042f : 1.0f;  // log2(e)/8 on Q
            u16* qk = (u16*)outp;
#pragma unroll
            for (int mf = 0; mf < 4; ++mf)
#pragma unroll
                for (int nf = 0; nf < 4; ++nf) {
                    const int col = wn * 64 + nf * 16 + fr;
#pragma unroll
                    for (int i = 0; i < 4; ++i) {
                        const int row  = wm * 64 + mf * 16 + g * 4 + i;
                        const int byte = row * 512 + ((col * 2) ^ (((row >> 2) & 3) << 5));
                        *reinterpret_cast<u16*>(sb + byte) = f2bf(acc[mf][nf][i] * osc);
                    }
                }
            __syncthreads();
            {
                const int row = tid >> 2;
                const int swz = ((row >> 2) & 3) << 5;
#pragma unroll
                for (int p = 0; p < 8; ++p) {
                    const int sl   = (tid & 3) + p * 4;
                    const int byte = row * 512 + ((sl * 16) ^ swz);
                    u16x8 v = *reinterpret_cast<const u16x8*>(sb + byte);
                    *reinterpret_cast<u16x8*>(
                        &qk[(size_t)(m0 + row) * 2048 + n0 + sl * 8]) = v;
                }
            }
        } else {
            const int bb = m0 >> 11, tloc = m0 & 2047;
#pragma unroll
            for (int mf = 0; mf < 4; ++mf)
#pragma unroll
                for (int nf = 0; nf < 4; ++nf) {
                    const int nl  = wn * 64 + nf * 16 + fr;
                    const int ml0 = wm * 64 + mf * 16 + g * 4;
                    const int f   = (nl & 7) << 5;
                    uint2 pk;
                    pk.x = cvtpk(acc[mf][nf][0], acc[mf][nf][1]);
                    pk.y = cvtpk(acc[mf][nf][2], acc[mf][nf][3]);
                    *reinterpret_cast<uint2*>(sb + nl * 256 + ((ml0 * 2) ^ f)) = pk;
                }
            __syncthreads();
            {
                const int nl = tid >> 1;
                const int f  = (nl & 7) << 5;
#pragma unroll
                for (int p = 0; p < 8; ++p) {
                    const int sl   = (tid & 1) + p * 2;
                    const int byte = nl * 256 + ((sl * 16) ^ f);
                    u16x8 v = *reinterpret_cast<const u16x8*>(sb + byte);
                    *reinterpret_cast<u16x8*>(
                        &vtg[(size_t)(bb * 1024 + (n0 - 2048) + nl) * 2048 +
                             tloc + sl * 8]) = v;
                }
            }
        }
    }
}

// ---------------- causal flash attention: 4-wave blocks, whole grid co-resident ----------------
// grid (1024), 256 thr: block = one 128-row q-tile; wave w owns rows w*32..w*32+31.
// qt via balance table: [15,12,2,1, 14,13,3,0, 11,8,6,5, 10,9,7,4] (groups of 4 sum 30).
__global__ __launch_bounds__(256, 4) void attn_fwd(const u16* __restrict__ qk,
                                                   const u16* __restrict__ vtg,
                                                   u16* __restrict__ Y) {
    constexpr int T = 2048, DQK = 2048, DOUT = 1024;
    const int idx = blockIdx.x;
    const int bh  = idx & 63;
    const int tsel = ((idx >> 6) & 3) * 4 + (idx >> 8);
    const int qt = (int)((0x479A568B03DE12CFull >> (tsel * 4)) & 15);
    const int b  = bh >> 4, hd = bh & 15;
    const int tid = threadIdx.x, w = tid >> 6, lane = tid & 63;
    const int qloc = lane & 31, h2 = lane >> 5;

    __shared__ u16 Ks[2][4096];   // [64 kv][64 d] linear, slot^(row&7) swizzle (8KB/buf)
    __shared__ u16 Vs[2][4096];   // [64 d][64 kv] linear, same swizzle

    const size_t rowb = (size_t)b * T;

    const int r0s = tid >> 3;                   // 0..31
    const int sc  = ((tid & 7) ^ (r0s & 7)) * 8;
    const int ldst = w * 512;                   // wave-uniform chunk base (u16)

    int off[4];
#pragma unroll
    for (int ks = 0; ks < 4; ++ks)
        off[ks] = qloc * 64 + (((2 * ks + h2) ^ (qloc & 7)) * 8);

#define BUILD_PA(sv, RB, dst) {                                               \
        unsigned wa  = cvtpk(sv[RB + 0], sv[RB + 1]);                         \
        unsigned wb2 = cvtpk(sv[RB + 2], sv[RB + 3]);                         \
        unsigned wc2 = cvtpk(sv[RB + 4], sv[RB + 5]);                         \
        unsigned wd  = cvtpk(sv[RB + 6], sv[RB + 7]);                         \
        u32x2 r0 = __builtin_amdgcn_permlane32_swap(wa, wc2, false, false);   \
        u32x2 r1 = __builtin_amdgcn_permlane32_swap(wb2, wd, false, false);   \
        dst.x = r0.x; dst.y = r1.x; dst.z = r0.y; dst.w = r1.y; }

#define PV_STEP(pa, KS, RBOFF, oacc) {                                        \
        bf16x8 vf_ = *reinterpret_cast<const bf16x8*>(&Vb[off[KS] + (RBOFF)]); \
        oacc = __builtin_amdgcn_mfma_f32_32x32x16_bf16(                       \
            *reinterpret_cast<const bf16x8*>(&pa), vf_, oacc, 0, 0, 0); }

    const int q0 = qt * 128;
    const int wq = q0 + w * 32;
    const int NT = 2 * qt + 2;

    bf16x8 qf[4];
#pragma unroll
    for (int ks = 0; ks < 4; ++ks)
        qf[ks] = *reinterpret_cast<const bf16x8*>(
            &qk[(rowb + wq + qloc) * DQK + hd * 64 + ks * 16 + h2 * 8]);

    f32x16 o0, o1;
#pragma unroll
    for (int i = 0; i < 16; ++i) { o0[i] = 0.f; o1[i] = 0.f; }
    float lp = 0.f;

    const u16* kp = qk  + (rowb + r0s) * DQK + 1024 + hd * 64 + sc;
    const u16* vp = vtg + ((size_t)bh * 64 + r0s) * T + sc;

    load_lds16(kp,            &Ks[0][ldst]);
    load_lds16(kp + 32 * DQK, &Ks[0][2048 + ldst]);
    load_lds16(vp,            &Vs[0][ldst]);
    load_lds16(vp + 32 * T,   &Vs[0][2048 + ldst]);
    kp += 64 * DQK; vp += 64;

    for (int kt = 0; kt < NT; ++kt) {
        __syncthreads();

        if (kt + 1 < NT) {
            const int nb = (kt + 1) & 1;
            load_lds16(kp,            &Ks[nb][ldst]);
            load_lds16(kp + 32 * DQK, &Ks[nb][2048 + ldst]);
            load_lds16(vp,            &Vs[nb][ldst]);
            load_lds16(vp + 32 * T,   &Vs[nb][2048 + ldst]);
            kp += 64 * DQK; vp += 64;
        }

        const int k0 = kt * 64;
        if (k0 <= wq + 31) {
            const u16* Kb = Ks[kt & 1];
            const u16* Vb = Vs[kt & 1];
            const bool do1 = (k0 + 32 <= wq + 31);
            const bool dm  = (k0 + 63 > wq);
            const int qg = wq + qloc;

            f32x16 st0, st1;
#pragma unroll
            for (int i = 0; i < 16; ++i) { st0[i] = 0.f; st1[i] = 0.f; }

            __builtin_amdgcn_s_setprio(1);
#pragma unroll
            for (int ks = 0; ks < 4; ++ks) {
                bf16x8 kf = *reinterpret_cast<const bf16x8*>(&Kb[off[ks]]);
                st0 = __builtin_amdgcn_mfma_f32_32x32x16_bf16(kf, qf[ks], st0, 0, 0, 0);
            }
            if (do1) {
#pragma unroll
                for (int ks = 0; ks < 4; ++ks) {
                    bf16x8 kf = *reinterpret_cast<const bf16x8*>(&Kb[off[ks] + 2048]);
                    st1 = __builtin_amdgcn_mfma_f32_32x32x16_bf16(kf, qf[ks], st1, 0, 0, 0);
                }
            }
            __builtin_amdgcn_s_setprio(0);

#pragma unroll
            for (int i = 0; i < 16; ++i) st0[i] = exp2v(st0[i]);
            if (dm) {
#pragma unroll
                for (int r = 0; r < 16; ++r) {
                    const int crow = (r & 3) + 8 * (r >> 2) + 4 * h2;
                    if (k0 + crow > qg) st0[r] = 0.f;
                }
            }
            {
                float l0 = 0.f, l1 = 0.f, l2 = 0.f, l3 = 0.f;
#pragma unroll
                for (int i = 0; i < 4; ++i) {
                    l0 += st0[i]; l1 += st0[4 + i]; l2 += st0[8 + i]; l3 += st0[12 + i];
                }
                lp += (l0 + l1) + (l2 + l3);
            }
            uint4 pa0, pa1;
            BUILD_PA(st0, 0, pa0);
            BUILD_PA(st0, 8, pa1);
            __builtin_amdgcn_s_setprio(1);
            PV_STEP(pa0, 0, 0, o0);
            PV_STEP(pa1, 1, 0, o0);
            PV_STEP(pa0, 0, 2048, o1);
            PV_STEP(pa1, 1, 2048, o1);
            __builtin_amdgcn_s_setprio(0);

            if (do1) {
#pragma unroll
                for (int i = 0; i < 16; ++i) st1[i] = exp2v(st1[i]);
                if (dm) {
#pragma unroll
                    for (int r = 0; r < 16; ++r) {
                        const int crow = (r & 3) + 8 * (r >> 2) + 4 * h2;
                        if (k0 + 32 + crow > qg) st1[r] = 0.f;
                    }
                }
                {
                    float l0 = 0.f, l1 = 0.f, l2 = 0.f, l3 = 0.f;
#pragma unroll
                    for (int i = 0; i < 4; ++i) {
                        l0 += st1[i]; l1 += st1[4 + i]; l2 += st1[8 + i]; l3 += st1[12 + i];
                    }
                    lp += (l0 + l1) + (l2 + l3);
                }
                uint4 pa2, pa3;
                BUILD_PA(st1, 0, pa2);
                BUILD_PA(st1, 8, pa3);
                __builtin_amdgcn_s_setprio(1);
                PV_STEP(pa2, 2, 0, o0);
                PV_STEP(pa3, 3, 0, o0);
                PV_STEP(pa2, 2, 2048, o1);
                PV_STEP(pa3, 3, 2048, o1);
                __builtin_amdgcn_s_setprio(0);
            }
        }
    }

    const float lf = lp + __shfl_xor(lp, 32);
    const float linv = 1.0f / lf;
#pragma unroll
    for (int r = 0; r < 16; ++r) {
        const int crow = (r & 3) + 8 * (r >> 2) + 4 * h2;
        const float rl = __shfl(linv, crow);
        const size_t yrow = rowb + wq + crow;
        Y[yrow * DOUT + hd * 64 + qloc]      = (u16)cvtpk(o0[r] * rl, 0.f);
        Y[yrow * DOUT + hd * 64 + 32 + qloc] = (u16)cvtpk(o1[r] * rl, 0.f);
    }
#undef BUILD_PA
#undef PV_STEP
}

extern "C" void kernel_launch(void* const* d_in, const int* in_sizes, int n_in,
                              void* d_out, int out_size, void* d_ws, size_t ws_size,
                              hipStream_t stream) {
    const float* x  = (const float*)d_in[0];
    const float* Wq = (const float*)d_in[1];
    const float* Wk = (const float*)d_in[2];
    const float* Wv = (const float*)d_in[3];
    const float* Wo = (const float*)d_in[4];

    constexpr int B = 4, T = 2048, D = 1024;
    constexpr int M = B * T;
    const int nx = in_sizes[0];
    const int nw = in_sizes[1];

    char* ws = (char*)d_ws;
    u16* xb   = (u16*)(ws);
    u16* qkb  = (u16*)(ws + (16ull << 20));
    u16* vtg  = (u16*)(ws + (48ull << 20));
    u16* yb   = (u16*)(ws + (64ull << 20));
    u16* wqkv = (u16*)(ws + (80ull << 20));   // Wq,Wk,Wv then Wo contiguous
    u16* wob  = wqkv + 3 * (size_t)nw;

    cast_f32_bf16<<<2048, 256, 0, stream>>>(x, xb, nx);
    cast_w4<<<dim3(256, 4), 256, 0, stream>>>(Wq, Wk, Wv, Wo, wqkv, nw);

    gemm128<1><<<dim3(M / 128, 3072 / 256), 512, 0, stream>>>(xb, wqkv, qkb, vtg, 3072, D);

    attn_fwd<<<dim3(1024), 256, 0, stream>>>(qkb, vtg, yb);

    gemm128<0><<<dim3(M / 128, D / 256), 512, 0, stream>>>(yb, wob, d_out, nullptr, D, D);
}

// Round 17
// 143.968 us; speedup vs baseline: 1.0166x; 1.0035x over previous
//
#include <hip/hip_runtime.h>
#include <cstdint>
#include <cstddef>

typedef unsigned short u16;
typedef short bf16x8 __attribute__((ext_vector_type(8)));
typedef unsigned short u16x8 __attribute__((ext_vector_type(8)));
typedef float f32x4 __attribute__((ext_vector_type(4)));
typedef float f32x16 __attribute__((ext_vector_type(16)));
typedef unsigned u32x2 __attribute__((ext_vector_type(2)));

__device__ __forceinline__ u16 f2bf(float x) {
    union { float f; unsigned int u; } v; v.f = x;
    unsigned int u = v.u;
    unsigned int r = (u + 0x7fffu + ((u >> 16) & 1u)) >> 16;
    return (u16)r;
}

__device__ __forceinline__ unsigned cvtpk(float lo, float hi) {
    unsigned r;
    asm("v_cvt_pk_bf16_f32 %0, %1, %2" : "=v"(r) : "v"(lo), "v"(hi));
    return r;
}

__device__ __forceinline__ float exp2v(float x) {
    float y;
    asm("v_exp_f32 %0, %1" : "=v"(y) : "v"(x));
    return y;
}

// async global->LDS, 16B per lane. dest = wave-uniform base; lane i lands at base + i*16B.
__device__ __forceinline__ void load_lds16(const void* g, void* l) {
    __builtin_amdgcn_global_load_lds((const __attribute__((address_space(1))) void*)g,
                                     (__attribute__((address_space(3))) void*)l, 16, 0, 0);
}

// ---------------- fused cast: x + 4 weights in one launch ----------------
__global__ void cast_all(const float* __restrict__ x,
                         const float* __restrict__ w0, const float* __restrict__ w1,
                         const float* __restrict__ w2, const float* __restrict__ w3,
                         u16* __restrict__ xb, u16* __restrict__ wout,
                         int nx, int nw) {
    const long total = (long)nx + 4L * nw;
    const long step  = 4L * (long)gridDim.x * blockDim.x;
    for (long i = 4L * ((long)blockIdx.x * blockDim.x + threadIdx.x); i < total; i += step) {
        const float* src;
        u16* dst;
        long off;
        if (i < nx) {
            src = x; dst = xb; off = i;
        } else {
            const long j = i - nx;
            const int  s = (int)(j / nw);
            off = j - (long)s * nw;
            src = (s == 0) ? w0 : (s == 1) ? w1 : (s == 2) ? w2 : w3;
            dst = wout + (size_t)s * nw;
        }
        float4 f = *reinterpret_cast<const float4*>(src + off);
        ushort4 o;
        o.x = f2bf(f.x); o.y = f2bf(f.y); o.z = f2bf(f.z); o.w = f2bf(f.w);
        *reinterpret_cast<ushort4*>(dst + off) = o;
    }
}

// ============ GEMM: 128x256 tile, BK=32, 512 thr, triple-buffered LDS (72KB) ============
// (R14 structure; counted vmcnt(3): 3 loads/thread/tile, next tile's 3 stay in flight.)
template <int MODE>
__global__ __launch_bounds__(512, 4) void gemm128(const u16* __restrict__ A,
                                                  const u16* __restrict__ Bw,
                                                  void* __restrict__ outp,
                                                  u16* __restrict__ vtg,
                                                  int N, int K) {
    __shared__ u16 smem[36864];   // 3 x (A 4096 + B 8192) u16 = 72 KB

    const int tid  = threadIdx.x;
    const int m0   = blockIdx.x * 128;
    const int n0   = blockIdx.y * 256;
    const int wid  = tid >> 6, lane = tid & 63;
    const int fr   = lane & 15, g = lane >> 4;
    const int wm   = wid >> 2, wn = wid & 3;

    const int r0   = tid >> 2;
    const int ssrc = (tid & 3) ^ ((r0 >> 1) & 3);
    const int wbu  = (tid & ~63) * 8;
    const u16* pA  = A  + (size_t)(m0 + r0) * K + ssrc * 8;
    const u16* pB0 = Bw + (size_t)(n0 + r0) * K + ssrc * 8;
    const u16* pB1 = Bw + (size_t)(n0 + r0 + 128) * K + ssrc * 8;

    int offA[4], offB[4];
#pragma unroll
    for (int mf = 0; mf < 4; ++mf) {
        const int row = wm * 64 + mf * 16 + fr;
        offA[mf] = row * 32 + (g ^ ((row >> 1) & 3)) * 8;
    }
#pragma unroll
    for (int nf = 0; nf < 4; ++nf) {
        const int row = wn * 64 + nf * 16 + fr;
        offB[nf] = 4096 + row * 32 + (g ^ ((row >> 1) & 3)) * 8;
    }

    f32x4 acc[4][4];
#pragma unroll
    for (int i = 0; i < 4; ++i)
#pragma unroll
        for (int j = 0; j < 4; ++j) acc[i][j] = f32x4{0.f, 0.f, 0.f, 0.f};

#define ISSUE(BUF) {                                                   \
        load_lds16(pA,  &smem[(BUF) * 12288 + wbu]);                   \
        load_lds16(pB0, &smem[(BUF) * 12288 + 4096 + wbu]);            \
        load_lds16(pB1, &smem[(BUF) * 12288 + 8192 + wbu]);            \
        pA += 32; pB0 += 32; pB1 += 32; }

    ISSUE(0);
    ISSUE(1);

    const int NT = K >> 5;
    int bu = 0;
    for (int t = 0; t < NT; ++t) {
        if (t < NT - 1) asm volatile("s_waitcnt vmcnt(3)\n\ts_barrier" ::: "memory");
        else            asm volatile("s_waitcnt vmcnt(0)\n\ts_barrier" ::: "memory");

        if (t + 2 < NT) {
            const int b2 = (bu == 0) ? 2 : bu - 1;
            ISSUE(b2);
        }

        const u16* Tb = &smem[bu * 12288];
        bf16x8 a[4], bv[4];
#pragma unroll
        for (int mf = 0; mf < 4; ++mf)
            a[mf] = *reinterpret_cast<const bf16x8*>(&Tb[offA[mf]]);
#pragma unroll
        for (int nf = 0; nf < 4; ++nf)
            bv[nf] = *reinterpret_cast<const bf16x8*>(&Tb[offB[nf]]);

        __builtin_amdgcn_s_setprio(1);
#pragma unroll
        for (int mf = 0; mf < 4; ++mf)
#pragma unroll
            for (int nf = 0; nf < 4; ++nf)
                acc[mf][nf] = __builtin_amdgcn_mfma_f32_16x16x32_bf16(
                    a[mf], bv[nf], acc[mf][nf], 0, 0, 0);
        __builtin_amdgcn_s_setprio(0);

        bu = (bu == 2) ? 0 : bu + 1;
    }
#undef ISSUE

    if constexpr (MODE == 0) {
        float* C = (float*)outp;
#pragma unroll
        for (int mf = 0; mf < 4; ++mf)
#pragma unroll
            for (int nf = 0; nf < 4; ++nf)
#pragma unroll
                for (int i = 0; i < 4; ++i)
                    C[(size_t)(m0 + wm * 64 + mf * 16 + g * 4 + i) * N +
                      n0 + wn * 64 + nf * 16 + fr] = acc[mf][nf][i];
    } else {
        __syncthreads();
        char* sb = reinterpret_cast<char*>(smem);
        if (n0 < 2048) {
            const float osc = (n0 < 1024) ? 0.18033688011112042f : 1.0f;  // log2(e)/8 on Q
            u16* qk = (u16*)outp;
#pragma unroll
            for (int mf = 0; mf < 4; ++mf)
#pragma unroll
                for (int nf = 0; nf < 4; ++nf) {
                    const int col = wn * 64 + nf * 16 + fr;
#pragma unroll
                    for (int i = 0; i < 4; ++i) {
                        const int row  = wm * 64 + mf * 16 + g * 4 + i;
                        const int byte = row * 512 + ((col * 2) ^ (((row >> 2) & 3) << 5));
                        *reinterpret_cast<u16*>(sb + byte) = f2bf(acc[mf][nf][i] * osc);
                    }
                }
            __syncthreads();
            {
                const int row = tid >> 2;
                const int swz = ((row >> 2) & 3) << 5;
#pragma unroll
                for (int p = 0; p < 8; ++p) {
                    const int sl   = (tid & 3) + p * 4;
                    const int byte = row * 512 + ((sl * 16) ^ swz);
                    u16x8 v = *reinterpret_cast<const u16x8*>(sb + byte);
                    *reinterpret_cast<u16x8*>(
                        &qk[(size_t)(m0 + row) * 2048 + n0 + sl * 8]) = v;
                }
            }
        } else {
            const int bb = m0 >> 11, tloc = m0 & 2047;
#pragma unroll
            for (int mf = 0; mf < 4; ++mf)
#pragma unroll
                for (int nf = 0; nf < 4; ++nf) {
                    const int nl  = wn * 64 + nf * 16 + fr;
                    const int ml0 = wm * 64 + mf * 16 + g * 4;
                    const int f   = (nl & 7) << 5;
                    uint2 pk;
                    pk.x = cvtpk(acc[mf][nf][0], acc[mf][nf][1]);
                    pk.y = cvtpk(acc[mf][nf][2], acc[mf][nf][3]);
                    *reinterpret_cast<uint2*>(sb + nl * 256 + ((ml0 * 2) ^ f)) = pk;
                }
            __syncthreads();
            {
                const int nl = tid >> 1;
                const int f  = (nl & 7) << 5;
#pragma unroll
                for (int p = 0; p < 8; ++p) {
                    const int sl   = (tid & 1) + p * 2;
                    const int byte = nl * 256 + ((sl * 16) ^ f);
                    u16x8 v = *reinterpret_cast<const u16x8*>(sb + byte);
                    *reinterpret_cast<u16x8*>(
                        &vtg[(size_t)(bb * 1024 + (n0 - 2048) + nl) * 2048 +
                             tloc + sl * 8]) = v;
                }
            }
        }
    }
}

// ---------------- causal flash attention: 4-wave blocks, whole grid co-resident ----------------
// grid (1024), 256 thr: block = one 128-row q-tile; wave w owns rows w*32..w*32+31.
// qt via balance table: [15,12,2,1, 14,13,3,0, 11,8,6,5, 10,9,7,4] (groups of 4 sum 30).
__global__ __launch_bounds__(256, 4) void attn_fwd(const u16* __restrict__ qk,
                                                   const u16* __restrict__ vtg,
                                                   u16* __restrict__ Y) {
    constexpr int T = 2048, DQK = 2048, DOUT = 1024;
    const int idx = blockIdx.x;
    const int bh  = idx & 63;
    const int tsel = ((idx >> 6) & 3) * 4 + (idx >> 8);
    const int qt = (int)((0x479A568B03DE12CFull >> (tsel * 4)) & 15);
    const int b  = bh >> 4, hd = bh & 15;
    const int tid = threadIdx.x, w = tid >> 6, lane = tid & 63;
    const int qloc = lane & 31, h2 = lane >> 5;

    __shared__ u16 Ks[2][4096];   // [64 kv][64 d] linear, slot^(row&7) swizzle (8KB/buf)
    __shared__ u16 Vs[2][4096];   // [64 d][64 kv] linear, same swizzle

    const size_t rowb = (size_t)b * T;

    const int r0s = tid >> 3;                   // 0..31
    const int sc  = ((tid & 7) ^ (r0s & 7)) * 8;
    const int ldst = w * 512;                   // wave-uniform chunk base (u16)

    int off[4];
#pragma unroll
    for (int ks = 0; ks < 4; ++ks)
        off[ks] = qloc * 64 + (((2 * ks + h2) ^ (qloc & 7)) * 8);

#define BUILD_PA(sv, RB, dst) {                                               \
        unsigned wa  = cvtpk(sv[RB + 0], sv[RB + 1]);                         \
        unsigned wb2 = cvtpk(sv[RB + 2], sv[RB + 3]);                         \
        unsigned wc2 = cvtpk(sv[RB + 4], sv[RB + 5]);                         \
        unsigned wd  = cvtpk(sv[RB + 6], sv[RB + 7]);                         \
        u32x2 r0 = __builtin_amdgcn_permlane32_swap(wa, wc2, false, false);   \
        u32x2 r1 = __builtin_amdgcn_permlane32_swap(wb2, wd, false, false);   \
        dst.x = r0.x; dst.y = r1.x; dst.z = r0.y; dst.w = r1.y; }

#define PV_STEP(pa, KS, RBOFF, oacc) {                                        \
        bf16x8 vf_ = *reinterpret_cast<const bf16x8*>(&Vb[off[KS] + (RBOFF)]); \
        oacc = __builtin_amdgcn_mfma_f32_32x32x16_bf16(                       \
            *reinterpret_cast<const bf16x8*>(&pa), vf_, oacc, 0, 0, 0); }

    const int q0 = qt * 128;
    const int wq = q0 + w * 32;
    const int NT = 2 * qt + 2;

    bf16x8 qf[4];
#pragma unroll
    for (int ks = 0; ks < 4; ++ks)
        qf[ks] = *reinterpret_cast<const bf16x8*>(
            &qk[(rowb + wq + qloc) * DQK + hd * 64 + ks * 16 + h2 * 8]);

    f32x16 o0, o1;
#pragma unroll
    for (int i = 0; i < 16; ++i) { o0[i] = 0.f; o1[i] = 0.f; }
    float lp = 0.f;

    const u16* kp = qk  + (rowb + r0s) * DQK + 1024 + hd * 64 + sc;
    const u16* vp = vtg + ((size_t)bh * 64 + r0s) * T + sc;

    load_lds16(kp,            &Ks[0][ldst]);
    load_lds16(kp + 32 * DQK, &Ks[0][2048 + ldst]);
    load_lds16(vp,            &Vs[0][ldst]);
    load_lds16(vp + 32 * T,   &Vs[0][2048 + ldst]);
    kp += 64 * DQK; vp += 64;

    for (int kt = 0; kt < NT; ++kt) {
        __syncthreads();

        if (kt + 1 < NT) {
            const int nb = (kt + 1) & 1;
            load_lds16(kp,            &Ks[nb][ldst]);
            load_lds16(kp + 32 * DQK, &Ks[nb][2048 + ldst]);
            load_lds16(vp,            &Vs[nb][ldst]);
            load_lds16(vp + 32 * T,   &Vs[nb][2048 + ldst]);
            kp += 64 * DQK; vp += 64;
        }

        const int k0 = kt * 64;
        if (k0 <= wq + 31) {
            const u16* Kb = Ks[kt & 1];
            const u16* Vb = Vs[kt & 1];
            const bool do1 = (k0 + 32 <= wq + 31);
            const bool dm  = (k0 + 63 > wq);
            const int qg = wq + qloc;

            f32x16 st0, st1;
#pragma unroll
            for (int i = 0; i < 16; ++i) { st0[i] = 0.f; st1[i] = 0.f; }

            __builtin_amdgcn_s_setprio(1);
#pragma unroll
            for (int ks = 0; ks < 4; ++ks) {
                bf16x8 kf = *reinterpret_cast<const bf16x8*>(&Kb[off[ks]]);
                st0 = __builtin_amdgcn_mfma_f32_32x32x16_bf16(kf, qf[ks], st0, 0, 0, 0);
            }
            if (do1) {
#pragma unroll
                for (int ks = 0; ks < 4; ++ks) {
                    bf16x8 kf = *reinterpret_cast<const bf16x8*>(&Kb[off[ks] + 2048]);
                    st1 = __builtin_amdgcn_mfma_f32_32x32x16_bf16(kf, qf[ks], st1, 0, 0, 0);
                }
            }
            __builtin_amdgcn_s_setprio(0);

#pragma unroll
            for (int i = 0; i < 16; ++i) st0[i] = exp2v(st0[i]);
            if (dm) {
#pragma unroll
                for (int r = 0; r < 16; ++r) {
                    const int crow = (r & 3) + 8 * (r >> 2) + 4 * h2;
                    if (k0 + crow > qg) st0[r] = 0.f;
                }
            }
            {
                float l0 = 0.f, l1 = 0.f, l2 = 0.f, l3 = 0.f;
#pragma unroll
                for (int i = 0; i < 4; ++i) {
                    l0 += st0[i]; l1 += st0[4 + i]; l2 += st0[8 + i]; l3 += st0[12 + i];
                }
                lp += (l0 + l1) + (l2 + l3);
            }
            uint4 pa0, pa1;
            BUILD_PA(st0, 0, pa0);
            BUILD_PA(st0, 8, pa1);
            __builtin_amdgcn_s_setprio(1);
            PV_STEP(pa0, 0, 0, o0);
            PV_STEP(pa1, 1, 0, o0);
            PV_STEP(pa0, 0, 2048, o1);
            PV_STEP(pa1, 1, 2048, o1);
            __builtin_amdgcn_s_setprio(0);

            if (do1) {
#pragma unroll
                for (int i = 0; i < 16; ++i) st1[i] = exp2v(st1[i]);
                if (dm) {
#pragma unroll
                    for (int r = 0; r < 16; ++r) {
                        const int crow = (r & 3) + 8 * (r >> 2) + 4 * h2;
                        if (k0 + 32 + crow > qg) st1[r] = 0.f;
                    }
                }
                {
                    float l0 = 0.f, l1 = 0.f, l2 = 0.f, l3 = 0.f;
#pragma unroll
                    for (int i = 0; i < 4; ++i) {
                        l0 += st1[i]; l1 += st1[4 + i]; l2 += st1[8 + i]; l3 += st1[12 + i];
                    }
                    lp += (l0 + l1) + (l2 + l3);
                }
                uint4 pa2, pa3;
                BUILD_PA(st1, 0, pa2);
                BUILD_PA(st1, 8, pa3);
                __builtin_amdgcn_s_setprio(1);
                PV_STEP(pa2, 2, 0, o0);
                PV_STEP(pa3, 3, 0, o0);
                PV_STEP(pa2, 2, 2048, o1);
                PV_STEP(pa3, 3, 2048, o1);
                __builtin_amdgcn_s_setprio(0);
            }
        }
    }

    const float lf = lp + __shfl_xor(lp, 32);
    const float linv = 1.0f / lf;
#pragma unroll
    for (int r = 0; r < 16; ++r) {
        const int crow = (r & 3) + 8 * (r >> 2) + 4 * h2;
        const float rl = __shfl(linv, crow);
        const size_t yrow = rowb + wq + crow;
        Y[yrow * DOUT + hd * 64 + qloc]      = (u16)cvtpk(o0[r] * rl, 0.f);
        Y[yrow * DOUT + hd * 64 + 32 + qloc] = (u16)cvtpk(o1[r] * rl, 0.f);
    }
#undef BUILD_PA
#undef PV_STEP
}

extern "C" void kernel_launch(void* const* d_in, const int* in_sizes, int n_in,
                              void* d_out, int out_size, void* d_ws, size_t ws_size,
                              hipStream_t stream) {
    const float* x  = (const float*)d_in[0];
    const float* Wq = (const float*)d_in[1];
    const float* Wk = (const float*)d_in[2];
    const float* Wv = (const float*)d_in[3];
    const float* Wo = (const float*)d_in[4];

    constexpr int B = 4, T = 2048, D = 1024;
    constexpr int M = B * T;
    const int nx = in_sizes[0];
    const int nw = in_sizes[1];

    char* ws = (char*)d_ws;
    u16* xb   = (u16*)(ws);
    u16* qkb  = (u16*)(ws + (16ull << 20));
    u16* vtg  = (u16*)(ws + (48ull << 20));
    u16* yb   = (u16*)(ws + (64ull << 20));
    u16* wqkv = (u16*)(ws + (80ull << 20));   // Wq,Wk,Wv then Wo contiguous
    u16* wob  = wqkv + 3 * (size_t)nw;

    cast_all<<<2048, 256, 0, stream>>>(x, Wq, Wk, Wv, Wo, xb, wqkv, nx, nw);

    gemm128<1><<<dim3(M / 128, 3072 / 256), 512, 0, stream>>>(xb, wqkv, qkb, vtg, 3072, D);

    attn_fwd<<<dim3(1024), 256, 0, stream>>>(qkb, vtg, yb);

    gemm128<0><<<dim3(M / 128, D / 256), 512, 0, stream>>>(yb, wob, d_out, nullptr, D, D);
}